// Round 3
// baseline (754.383 us; speedup 1.0000x reference)
//
#include <hip/hip_runtime.h>

#define BN 16384
#define DD 16
#define KNN 25
#define QB 8
#define MSUB 2048
#define CAP 768

typedef unsigned long long u64;

__device__ __forceinline__ u64 wave_min_u64(u64 v) {
#pragma unroll
    for (int off = 32; off >= 1; off >>= 1) {
        unsigned lo = (unsigned)v, hi = (unsigned)(v >> 32);
        unsigned olo = __shfl_xor(lo, off, 64);
        unsigned ohi = __shfl_xor(hi, off, 64);
        u64 o = (((u64)ohi) << 32) | olo;
        if (o < v) v = o;
    }
    return v;
}

// ---------------- norms: |raw_j|^2 ----------------
__global__ void norms_kernel(const float* __restrict__ raw, float* __restrict__ nrm) {
    int j = blockIdx.x * 256 + threadIdx.x;
    if (j < BN) {
        const float4* rv = (const float4*)raw + j * 4;
        float s = 0.f;
#pragma unroll
        for (int i = 0; i < 4; ++i) {
            float4 v = rv[i];
            s = fmaf(v.x, v.x, s); s = fmaf(v.y, v.y, s);
            s = fmaf(v.z, v.z, s); s = fmaf(v.w, v.w, s);
        }
        nrm[j] = s;
    }
}

// ---------------- recon partials ----------------
__global__ void recon_kernel(const float* __restrict__ o, const float* __restrict__ t,
                             float* __restrict__ part) {
    __shared__ float red[256];
    int tid = threadIdx.x;
    int idx = blockIdx.x * 256 + tid;
    float s = 0.f;
    for (int i = idx; i < BN * DD; i += 256 * 256) {
        float d = o[i] - t[i];
        s = fmaf(d, d, s);
    }
    red[tid] = s;
    __syncthreads();
    for (int off = 128; off > 0; off >>= 1) {
        if (tid < off) red[tid] += red[tid + off];
        __syncthreads();
    }
    if (tid == 0) part[blockIdx.x] = red[0];
}

// ---------------- main: 8 rows per block ----------------
__global__ __launch_bounds__(256, 2) void tsa_kernel(const float* __restrict__ latent,
                                                     const float* __restrict__ raw,
                                                     const float* __restrict__ nrm,
                                                     float* __restrict__ tsa) {
    const int tid  = threadIdx.x;
    const int lane = tid & 63;
    const int w    = tid >> 6;
    const int row0 = blockIdx.x * QB;

    // 48 KB region: phase A = minbuf (16 KB), phase B = candidate lists,
    // eigen phase = per-wave scratch. Overlays separated by __syncthreads().
    __shared__ __align__(16) char smem[QB * CAP * 8];
    float (*listV)[CAP] = (float (*)[CAP])smem;
    int   (*listI)[CAP] = (int (*)[CAP])(smem + QB * CAP * 4);
    u64   (*minbuf)[256] = (u64 (*)[256])smem;

    __shared__ float qstage[QB][DD];
    __shared__ int   lcnt[QB];
    __shared__ float Bv[QB];
    __shared__ int   nbr[QB][KNN];

    if (tid < QB) lcnt[tid] = 0;
    if (tid < QB * DD) ((float*)qstage)[tid] = raw[row0 * DD + tid];
    __syncthreads();

    // queries -> registers (stay resident: 256-VGPR budget)
    float qd[QB][DD];
    float qn[QB];
#pragma unroll
    for (int qi = 0; qi < QB; ++qi) {
        float s = 0.f;
#pragma unroll
        for (int d = 0; d < DD; ++d) {
            float v = qstage[qi][d];
            qd[qi][d] = v;
            s = fmaf(v, v, s);
        }
        qn[qi] = s;
    }

    // ---- phase A: per-thread min over subset [0, MSUB) ----
    u64 kmin[QB];
#pragma unroll
    for (int qi = 0; qi < QB; ++qi) kmin[qi] = ~0ull;

    for (int j = tid; j < MSUB; j += 256) {
        const float4* pv = (const float4*)raw + j * 4;
        float4 a = pv[0], b = pv[1], c = pv[2], e = pv[3];
        float p[16] = {a.x,a.y,a.z,a.w,b.x,b.y,b.z,b.w,c.x,c.y,c.z,c.w,e.x,e.y,e.z,e.w};
        float pn = nrm[j];
#pragma unroll
        for (int qi = 0; qi < QB; ++qi) {
            float acc = 0.f;
#pragma unroll
            for (int d = 0; d < DD; ++d) acc = fmaf(qd[qi][d], p[d], acc);
            float d2 = fmaxf(fmaf(-2.f, acc, qn[qi] + pn), 0.f);
            u64 key = (((u64)__float_as_uint(d2)) << 32) | (unsigned)j;
            if (j != row0 + qi && key < kmin[qi]) kmin[qi] = key;
        }
    }
#pragma unroll
    for (int qi = 0; qi < QB; ++qi) minbuf[qi][tid] = kmin[qi];
    __syncthreads();

    // ---- bound: 25th smallest of the 256 per-thread mins (wave-local) ----
    for (int qq = 0; qq < 2; ++qq) {
        int qi = 2 * w + qq;
        u64 v0 = minbuf[qi][lane];
        u64 v1 = minbuf[qi][lane + 64];
        u64 v2 = minbuf[qi][lane + 128];
        u64 v3 = minbuf[qi][lane + 192];
        u64 bk = ~0ull;
        for (int it = 0; it < KNN; ++it) {
            u64 m = v0 < v1 ? v0 : v1;
            u64 m2 = v2 < v3 ? v2 : v3;
            if (m2 < m) m = m2;
            m = wave_min_u64(m);
            bk = m;
            if (v0 == m) v0 = ~0ull;
            if (v1 == m) v1 = ~0ull;
            if (v2 == m) v2 = ~0ull;
            if (v3 == m) v3 = ~0ull;
        }
        if (lane == 0) Bv[qi] = __uint_as_float((unsigned)(bk >> 32));
    }
    __syncthreads();

    float b_[QB];
#pragma unroll
    for (int qi = 0; qi < QB; ++qi) b_[qi] = Bv[qi];

    // ---- phase B: single full pass, collect d2 <= B ----
    for (int j = tid; j < BN; j += 256) {
        const float4* pv = (const float4*)raw + j * 4;
        float4 a = pv[0], b = pv[1], c = pv[2], e = pv[3];
        float p[16] = {a.x,a.y,a.z,a.w,b.x,b.y,b.z,b.w,c.x,c.y,c.z,c.w,e.x,e.y,e.z,e.w};
        float pn = nrm[j];
#pragma unroll
        for (int qi = 0; qi < QB; ++qi) {
            float acc = 0.f;
#pragma unroll
            for (int d = 0; d < DD; ++d) acc = fmaf(qd[qi][d], p[d], acc);
            float d2 = fmaxf(fmaf(-2.f, acc, qn[qi] + pn), 0.f);
            if (d2 <= b_[qi] && j != row0 + qi) {
                int pos = atomicAdd(&lcnt[qi], 1);
                if (pos < CAP) { listV[qi][pos] = d2; listI[qi][pos] = j; }
            }
        }
    }
    __syncthreads();

    // ---- exact top-25 per query (wave-local, (d2,idx) tie-break) ----
    for (int qq = 0; qq < 2; ++qq) {
        int qi = 2 * w + qq;
        int cnt = lcnt[qi]; if (cnt > CAP) cnt = CAP;
        for (int it = 0; it < KNN; ++it) {
            u64 best = ~0ull;
            for (int e = lane; e < cnt; e += 64) {
                u64 key = (((u64)__float_as_uint(listV[qi][e])) << 32) |
                          (unsigned)listI[qi][e];
                if (key < best) best = key;
            }
            best = wave_min_u64(best);
            int wj = (int)(best & 0xffffffffu);
            for (int e = lane; e < cnt; e += 64)
                if (listI[qi][e] == wj) listV[qi][e] = __builtin_inff();
            if (lane == 0) nbr[qi][it] = wj;
        }
    }
    __syncthreads();   // lists dead; eigen scratch overlays them

    // ---- eigen phase: wave w owns rows 2w, 2w+1 ----
    float* ws  = (float*)smem + w * 1024;
    float* pts = ws;            // 400
    float* Am0 = ws + 400;      // 256
    float* Bm0 = ws + 656;      // 256
    float* vv  = ws + 912;      // 16
    float* mn  = ws + 928;      // 16
    float* uv  = ws + 944;      // 32

    for (int rr = 0; rr < 2; ++rr) {
        int qi = 2 * w + rr;
        for (int m = 0; m < 2; ++m) {
            const float* src = (m == 0) ? latent : raw;
            for (int e = lane; e < KNN * DD; e += 64)
                pts[e] = src[nbr[qi][e >> 4] * DD + (e & 15)];
            __syncthreads();
            if (lane < DD) {
                float s = 0.f;
#pragma unroll
                for (int k = 0; k < KNN; ++k) s += pts[k * DD + lane];
                mn[lane] = s * (1.0f / KNN);
            }
            __syncthreads();
            for (int e = lane; e < KNN * DD; e += 64) pts[e] -= mn[e & 15];
            __syncthreads();
#pragma unroll
            for (int s4 = 0; s4 < 4; ++s4) {
                int e = lane + 64 * s4;
                int i = e >> 4, jj = e & 15;
                float s = 0.f;
#pragma unroll
                for (int k = 0; k < KNN; ++k) s = fmaf(pts[k * DD + i], pts[k * DD + jj], s);
                Am0[e] = s;
            }
            __syncthreads();

            float* A = Am0;
            float* B = Bm0;
            for (int sq = 0; sq < 5; ++sq) {
                float t = (lane < DD) ? A[lane * 17] : 0.f;
#pragma unroll
                for (int off = 32; off >= 1; off >>= 1) t += __shfl_xor(t, off, 64);
                float itr = (t > 0.f) ? (1.0f / t) : 1.0f;
#pragma unroll
                for (int s4 = 0; s4 < 4; ++s4) {
                    int e = lane + 64 * s4;
                    int i = e >> 4, jj = e & 15;
                    float s = 0.f;
#pragma unroll
                    for (int k = 0; k < DD; ++k) s = fmaf(A[i * DD + k], A[k * DD + jj], s);
                    B[e] = s * itr * itr;
                }
                __syncthreads();
                float* tmp = A; A = B; B = tmp;
            }

            // column with largest norm (tie: lower j)
            float cn = -1.f;
            if (lane < DD) {
                cn = 0.f;
#pragma unroll
                for (int i = 0; i < DD; ++i) { float c = A[i * DD + lane]; cn = fmaf(c, c, cn); }
            }
            int bj = lane & 15;
#pragma unroll
            for (int off = 32; off >= 1; off >>= 1) {
                float on = __shfl_xor(cn, off, 64);
                int   oj = __shfl_xor(bj, off, 64);
                if (on > cn || (on == cn && oj < bj)) { cn = on; bj = oj; }
            }
            if (lane < DD) vv[lane] = A[lane * DD + bj];
            __syncthreads();

            for (int pit = 0; pit < 2; ++pit) {
                float s = 0.f;
                if (lane < DD) {
#pragma unroll
                    for (int jj = 0; jj < DD; ++jj) s = fmaf(A[lane * DD + jj], vv[jj], s);
                }
                __syncthreads();
                if (lane < DD) vv[lane] = s;
                __syncthreads();
            }

            float nv = (lane < DD) ? vv[lane] * vv[lane] : 0.f;
#pragma unroll
            for (int off = 32; off >= 1; off >>= 1) nv += __shfl_xor(nv, off, 64);
            float inv = rsqrtf(fmaxf(nv, 1e-30f));
            if (lane < DD) uv[m * DD + lane] = vv[lane] * inv;
            __syncthreads();
        }
        float dt = (lane < DD) ? uv[lane] * uv[DD + lane] : 0.f;
#pragma unroll
        for (int off = 32; off >= 1; off >>= 1) dt += __shfl_xor(dt, off, 64);
        if (lane == 0) tsa[row0 + qi] = 2.0f - 2.0f * dt * dt;
        __syncthreads();
    }
}

// ---------------- finalize ----------------
__global__ void finalize_kernel(const float* __restrict__ tsa,
                                const float* __restrict__ part,
                                float* __restrict__ out) {
    __shared__ float red[256];
    int tid = threadIdx.x;
    float s = 0.f;
    for (int i = tid; i < BN; i += 256) s += tsa[i];
    red[tid] = s;
    __syncthreads();
    for (int off = 128; off > 0; off >>= 1) {
        if (tid < off) red[tid] += red[tid + off];
        __syncthreads();
    }
    float tsaSum = red[0];
    __syncthreads();
    red[tid] = part[tid];
    __syncthreads();
    for (int off = 128; off > 0; off >>= 1) {
        if (tid < off) red[tid] += red[tid + off];
        __syncthreads();
    }
    if (tid == 0)
        out[0] = red[0] * (1.0f / (float)(BN * DD)) + 0.1f * (tsaSum * (1.0f / (float)BN));
}

extern "C" void kernel_launch(void* const* d_in, const int* in_sizes, int n_in,
                              void* d_out, int out_size, void* d_ws, size_t ws_size,
                              hipStream_t stream) {
    const float* outputs = (const float*)d_in[0];
    const float* targets = (const float*)d_in[1];
    const float* latent  = (const float*)d_in[2];
    const float* raw     = (const float*)d_in[3];
    float* ws_f = (float*)d_ws;
    float* tsa  = ws_f;            // BN
    float* part = ws_f + BN;       // 256
    float* nrm  = ws_f + BN + 256; // BN

    norms_kernel<<<BN / 256, 256, 0, stream>>>(raw, nrm);
    recon_kernel<<<256, 256, 0, stream>>>(outputs, targets, part);
    tsa_kernel<<<BN / QB, 256, 0, stream>>>(latent, raw, nrm, tsa);
    finalize_kernel<<<1, 256, 0, stream>>>(tsa, part, (float*)d_out);
}

// Round 4
// 643.629 us; speedup vs baseline: 1.1721x; 1.1721x over previous
//
#include <hip/hip_runtime.h>

#define BN 16384
#define DD 16
#define KNN 25
#define QB 8
#define MSUB 2048
#define CAP 768

typedef unsigned long long u64;

__device__ __forceinline__ u64 wave_min_u64(u64 v) {
#pragma unroll
    for (int off = 32; off >= 1; off >>= 1) {
        unsigned lo = (unsigned)v, hi = (unsigned)(v >> 32);
        unsigned olo = __shfl_xor(lo, off, 64);
        unsigned ohi = __shfl_xor(hi, off, 64);
        u64 o = (((u64)ohi) << 32) | olo;
        if (o < v) v = o;
    }
    return v;
}

// ---------------- norms: |raw_j|^2 ----------------
__global__ void norms_kernel(const float* __restrict__ raw, float* __restrict__ nrm) {
    int j = blockIdx.x * 256 + threadIdx.x;
    if (j < BN) {
        const float4* rv = (const float4*)raw + j * 4;
        float s = 0.f;
#pragma unroll
        for (int i = 0; i < 4; ++i) {
            float4 v = rv[i];
            s = fmaf(v.x, v.x, s); s = fmaf(v.y, v.y, s);
            s = fmaf(v.z, v.z, s); s = fmaf(v.w, v.w, s);
        }
        nrm[j] = s;
    }
}

// ---------------- recon partials ----------------
__global__ void recon_kernel(const float* __restrict__ o, const float* __restrict__ t,
                             float* __restrict__ part) {
    __shared__ float red[256];
    int tid = threadIdx.x;
    int idx = blockIdx.x * 256 + tid;
    float s = 0.f;
    for (int i = idx; i < BN * DD; i += 256 * 256) {
        float d = o[i] - t[i];
        s = fmaf(d, d, s);
    }
    red[tid] = s;
    __syncthreads();
    for (int off = 128; off > 0; off >>= 1) {
        if (tid < off) red[tid] += red[tid + off];
        __syncthreads();
    }
    if (tid == 0) part[blockIdx.x] = red[0];
}

// 16-term fma dot of query regs (qa..qd) with point regs (pa..pd)
#define DOT16(qa,qb,qc,qd) \
    fmaf(qd.w, pd.w, fmaf(qd.z, pd.z, fmaf(qd.y, pd.y, fmaf(qd.x, pd.x, \
    fmaf(qc.w, pc.w, fmaf(qc.z, pc.z, fmaf(qc.y, pc.y, fmaf(qc.x, pc.x, \
    fmaf(qb.w, pb.w, fmaf(qb.z, pb.z, fmaf(qb.y, pb.y, fmaf(qb.x, pb.x, \
    fmaf(qa.w, pa.w, fmaf(qa.z, pa.z, fmaf(qa.y, pa.y, qa.x * pa.x)))))))))))))))

// ---------------- main: 8 rows per block, queries in named registers ----------------
__global__ __launch_bounds__(256, 2) void tsa_kernel(const float* __restrict__ latent,
                                                     const float* __restrict__ raw,
                                                     const float* __restrict__ nrm,
                                                     float* __restrict__ tsa) {
    const int tid  = threadIdx.x;
    const int lane = tid & 63;
    const int w    = tid >> 6;
    const int row0 = blockIdx.x * QB;

    // 48 KB overlay region: phase A = minbuf, phase B = candidate lists,
    // eigen phase = per-wave scratch.
    __shared__ __align__(16) char smem[QB * CAP * 8];
    float (*listV)[CAP] = (float (*)[CAP])smem;
    int   (*listI)[CAP] = (int (*)[CAP])(smem + QB * CAP * 4);
    u64   (*minbuf)[256] = (u64 (*)[256])smem;

    __shared__ int   lcnt[QB];
    __shared__ float Bv[QB];
    __shared__ int   nbr[QB][KNN];

    if (tid < QB) lcnt[tid] = 0;
    __syncthreads();

    const float4* rv4 = (const float4*)raw;

    // ---- queries -> NAMED registers (global broadcast loads, no LDS) ----
#define LQ(qi) \
    float4 q##qi##a = rv4[(row0 + qi) * 4 + 0]; \
    float4 q##qi##b = rv4[(row0 + qi) * 4 + 1]; \
    float4 q##qi##c = rv4[(row0 + qi) * 4 + 2]; \
    float4 q##qi##d = rv4[(row0 + qi) * 4 + 3]; \
    float qn##qi; { \
        float s = q##qi##a.x * q##qi##a.x; \
        s = fmaf(q##qi##a.y, q##qi##a.y, s); s = fmaf(q##qi##a.z, q##qi##a.z, s); \
        s = fmaf(q##qi##a.w, q##qi##a.w, s); s = fmaf(q##qi##b.x, q##qi##b.x, s); \
        s = fmaf(q##qi##b.y, q##qi##b.y, s); s = fmaf(q##qi##b.z, q##qi##b.z, s); \
        s = fmaf(q##qi##b.w, q##qi##b.w, s); s = fmaf(q##qi##c.x, q##qi##c.x, s); \
        s = fmaf(q##qi##c.y, q##qi##c.y, s); s = fmaf(q##qi##c.z, q##qi##c.z, s); \
        s = fmaf(q##qi##c.w, q##qi##c.w, s); s = fmaf(q##qi##d.x, q##qi##d.x, s); \
        s = fmaf(q##qi##d.y, q##qi##d.y, s); s = fmaf(q##qi##d.z, q##qi##d.z, s); \
        s = fmaf(q##qi##d.w, q##qi##d.w, s); qn##qi = s; }
    LQ(0) LQ(1) LQ(2) LQ(3) LQ(4) LQ(5) LQ(6) LQ(7)

    // ---- phase A: per-thread min over subset [0, MSUB) ----
    u64 km0 = ~0ull, km1 = ~0ull, km2 = ~0ull, km3 = ~0ull;
    u64 km4 = ~0ull, km5 = ~0ull, km6 = ~0ull, km7 = ~0ull;

    for (int j = tid; j < MSUB; j += 256) {
        float4 pa = rv4[j * 4 + 0], pb = rv4[j * 4 + 1];
        float4 pc = rv4[j * 4 + 2], pd = rv4[j * 4 + 3];
        float pn = nrm[j];
#define PHA(qi) { \
        float acc = DOT16(q##qi##a, q##qi##b, q##qi##c, q##qi##d); \
        float d2 = fmaxf(fmaf(-2.f, acc, qn##qi + pn), 0.f); \
        u64 key = (((u64)__float_as_uint(d2)) << 32) | (unsigned)j; \
        if (j != row0 + qi && key < km##qi) km##qi = key; }
        PHA(0) PHA(1) PHA(2) PHA(3) PHA(4) PHA(5) PHA(6) PHA(7)
    }
    minbuf[0][tid] = km0; minbuf[1][tid] = km1; minbuf[2][tid] = km2; minbuf[3][tid] = km3;
    minbuf[4][tid] = km4; minbuf[5][tid] = km5; minbuf[6][tid] = km6; minbuf[7][tid] = km7;
    __syncthreads();

    // ---- bound: 25th smallest of the 256 per-thread mins (wave-local) ----
    for (int qq = 0; qq < 2; ++qq) {
        int qi = 2 * w + qq;
        u64 v0 = minbuf[qi][lane];
        u64 v1 = minbuf[qi][lane + 64];
        u64 v2 = minbuf[qi][lane + 128];
        u64 v3 = minbuf[qi][lane + 192];
        u64 bk = ~0ull;
        for (int it = 0; it < KNN; ++it) {
            u64 m = v0 < v1 ? v0 : v1;
            u64 m2 = v2 < v3 ? v2 : v3;
            if (m2 < m) m = m2;
            m = wave_min_u64(m);
            bk = m;
            if (v0 == m) v0 = ~0ull;
            if (v1 == m) v1 = ~0ull;
            if (v2 == m) v2 = ~0ull;
            if (v3 == m) v3 = ~0ull;
        }
        if (lane == 0) Bv[qi] = __uint_as_float((unsigned)(bk >> 32));
    }
    __syncthreads();

    float b0 = Bv[0], b1 = Bv[1], b2 = Bv[2], b3 = Bv[3];
    float b4 = Bv[4], b5 = Bv[5], b6 = Bv[6], b7 = Bv[7];

    // ---- phase B: single full pass, collect d2 <= B ----
    for (int j = tid; j < BN; j += 256) {
        float4 pa = rv4[j * 4 + 0], pb = rv4[j * 4 + 1];
        float4 pc = rv4[j * 4 + 2], pd = rv4[j * 4 + 3];
        float pn = nrm[j];
#define PHB(qi) { \
        float acc = DOT16(q##qi##a, q##qi##b, q##qi##c, q##qi##d); \
        float d2 = fmaxf(fmaf(-2.f, acc, qn##qi + pn), 0.f); \
        if (d2 <= b##qi && j != row0 + qi) { \
            int pos = atomicAdd(&lcnt[qi], 1); \
            if (pos < CAP) { listV[qi][pos] = d2; listI[qi][pos] = j; } } }
        PHB(0) PHB(1) PHB(2) PHB(3) PHB(4) PHB(5) PHB(6) PHB(7)
    }
    __syncthreads();

    // ---- exact top-25 per query (wave-local, (d2,idx) tie-break) ----
    for (int qq = 0; qq < 2; ++qq) {
        int qi = 2 * w + qq;
        int cnt = lcnt[qi]; if (cnt > CAP) cnt = CAP;
        for (int it = 0; it < KNN; ++it) {
            u64 best = ~0ull;
            for (int e = lane; e < cnt; e += 64) {
                u64 key = (((u64)__float_as_uint(listV[qi][e])) << 32) |
                          (unsigned)listI[qi][e];
                if (key < best) best = key;
            }
            best = wave_min_u64(best);
            int wj = (int)(best & 0xffffffffu);
            for (int e = lane; e < cnt; e += 64)
                if (listI[qi][e] == wj) listV[qi][e] = __builtin_inff();
            if (lane == 0) nbr[qi][it] = wj;
        }
    }
    __syncthreads();   // lists dead; eigen scratch overlays them

    // ---- eigen phase: wave w owns rows 2w, 2w+1 ----
    float* ws  = (float*)smem + w * 1024;
    float* pts = ws;            // 400
    float* Am0 = ws + 400;      // 256
    float* Bm0 = ws + 656;      // 256
    float* vv  = ws + 912;      // 16
    float* mn  = ws + 928;      // 16
    float* uv  = ws + 944;      // 32

    for (int rr = 0; rr < 2; ++rr) {
        int qi = 2 * w + rr;
        for (int m = 0; m < 2; ++m) {
            const float* src = (m == 0) ? latent : raw;
            for (int e = lane; e < KNN * DD; e += 64)
                pts[e] = src[nbr[qi][e >> 4] * DD + (e & 15)];
            __syncthreads();
            if (lane < DD) {
                float s = 0.f;
#pragma unroll
                for (int k = 0; k < KNN; ++k) s += pts[k * DD + lane];
                mn[lane] = s * (1.0f / KNN);
            }
            __syncthreads();
            for (int e = lane; e < KNN * DD; e += 64) pts[e] -= mn[e & 15];
            __syncthreads();
#pragma unroll
            for (int s4 = 0; s4 < 4; ++s4) {
                int e = lane + 64 * s4;
                int i = e >> 4, jj = e & 15;
                float s = 0.f;
#pragma unroll
                for (int k = 0; k < KNN; ++k) s = fmaf(pts[k * DD + i], pts[k * DD + jj], s);
                Am0[e] = s;
            }
            __syncthreads();

            float* A = Am0;
            float* B = Bm0;
            for (int sq = 0; sq < 5; ++sq) {
                float t = (lane < DD) ? A[lane * 17] : 0.f;
#pragma unroll
                for (int off = 32; off >= 1; off >>= 1) t += __shfl_xor(t, off, 64);
                float itr = (t > 0.f) ? (1.0f / t) : 1.0f;
#pragma unroll
                for (int s4 = 0; s4 < 4; ++s4) {
                    int e = lane + 64 * s4;
                    int i = e >> 4, jj = e & 15;
                    float s = 0.f;
#pragma unroll
                    for (int k = 0; k < DD; ++k) s = fmaf(A[i * DD + k], A[k * DD + jj], s);
                    B[e] = s * itr * itr;
                }
                __syncthreads();
                float* tmp = A; A = B; B = tmp;
            }

            // column with largest norm (tie: lower j)
            float cn = -1.f;
            if (lane < DD) {
                cn = 0.f;
#pragma unroll
                for (int i = 0; i < DD; ++i) { float c = A[i * DD + lane]; cn = fmaf(c, c, cn); }
            }
            int bj = lane & 15;
#pragma unroll
            for (int off = 32; off >= 1; off >>= 1) {
                float on = __shfl_xor(cn, off, 64);
                int   oj = __shfl_xor(bj, off, 64);
                if (on > cn || (on == cn && oj < bj)) { cn = on; bj = oj; }
            }
            if (lane < DD) vv[lane] = A[lane * DD + bj];
            __syncthreads();

            for (int pit = 0; pit < 2; ++pit) {
                float s = 0.f;
                if (lane < DD) {
#pragma unroll
                    for (int jj = 0; jj < DD; ++jj) s = fmaf(A[lane * DD + jj], vv[jj], s);
                }
                __syncthreads();
                if (lane < DD) vv[lane] = s;
                __syncthreads();
            }

            float nv = (lane < DD) ? vv[lane] * vv[lane] : 0.f;
#pragma unroll
            for (int off = 32; off >= 1; off >>= 1) nv += __shfl_xor(nv, off, 64);
            float inv = rsqrtf(fmaxf(nv, 1e-30f));
            if (lane < DD) uv[m * DD + lane] = vv[lane] * inv;
            __syncthreads();
        }
        float dt = (lane < DD) ? uv[lane] * uv[DD + lane] : 0.f;
#pragma unroll
        for (int off = 32; off >= 1; off >>= 1) dt += __shfl_xor(dt, off, 64);
        if (lane == 0) tsa[row0 + qi] = 2.0f - 2.0f * dt * dt;
        __syncthreads();
    }
}

// ---------------- finalize ----------------
__global__ void finalize_kernel(const float* __restrict__ tsa,
                                const float* __restrict__ part,
                                float* __restrict__ out) {
    __shared__ float red[256];
    int tid = threadIdx.x;
    float s = 0.f;
    for (int i = tid; i < BN; i += 256) s += tsa[i];
    red[tid] = s;
    __syncthreads();
    for (int off = 128; off > 0; off >>= 1) {
        if (tid < off) red[tid] += red[tid + off];
        __syncthreads();
    }
    float tsaSum = red[0];
    __syncthreads();
    red[tid] = part[tid];
    __syncthreads();
    for (int off = 128; off > 0; off >>= 1) {
        if (tid < off) red[tid] += red[tid + off];
        __syncthreads();
    }
    if (tid == 0)
        out[0] = red[0] * (1.0f / (float)(BN * DD)) + 0.1f * (tsaSum * (1.0f / (float)BN));
}

extern "C" void kernel_launch(void* const* d_in, const int* in_sizes, int n_in,
                              void* d_out, int out_size, void* d_ws, size_t ws_size,
                              hipStream_t stream) {
    const float* outputs = (const float*)d_in[0];
    const float* targets = (const float*)d_in[1];
    const float* latent  = (const float*)d_in[2];
    const float* raw     = (const float*)d_in[3];
    float* ws_f = (float*)d_ws;
    float* tsa  = ws_f;            // BN
    float* part = ws_f + BN;       // 256
    float* nrm  = ws_f + BN + 256; // BN

    norms_kernel<<<BN / 256, 256, 0, stream>>>(raw, nrm);
    recon_kernel<<<256, 256, 0, stream>>>(outputs, targets, part);
    tsa_kernel<<<BN / QB, 256, 0, stream>>>(latent, raw, nrm, tsa);
    finalize_kernel<<<1, 256, 0, stream>>>(tsa, part, (float*)d_out);
}

// Round 5
// 480.732 us; speedup vs baseline: 1.5692x; 1.3389x over previous
//
#include <hip/hip_runtime.h>

#define BN 16384
#define DD 16
#define KNN 25
#define QB 8
#define MSUB 2048
#define CAP 576

typedef unsigned long long u64;

__device__ __forceinline__ u64 wave_min_u64(u64 v) {
#pragma unroll
    for (int off = 32; off >= 1; off >>= 1) {
        unsigned lo = (unsigned)v, hi = (unsigned)(v >> 32);
        unsigned olo = __shfl_xor(lo, off, 64);
        unsigned ohi = __shfl_xor(hi, off, 64);
        u64 o = (((u64)ohi) << 32) | olo;
        if (o < v) v = o;
    }
    return v;
}

// ---------------- norms: |raw_j|^2 ----------------
__global__ void norms_kernel(const float* __restrict__ raw, float* __restrict__ nrm) {
    int j = blockIdx.x * 256 + threadIdx.x;
    if (j < BN) {
        const float4* rv = (const float4*)raw + j * 4;
        float s = 0.f;
#pragma unroll
        for (int i = 0; i < 4; ++i) {
            float4 v = rv[i];
            s = fmaf(v.x, v.x, s); s = fmaf(v.y, v.y, s);
            s = fmaf(v.z, v.z, s); s = fmaf(v.w, v.w, s);
        }
        nrm[j] = s;
    }
}

// ---------------- recon partials ----------------
__global__ void recon_kernel(const float* __restrict__ o, const float* __restrict__ t,
                             float* __restrict__ part) {
    __shared__ float red[256];
    int tid = threadIdx.x;
    int idx = blockIdx.x * 256 + tid;
    float s = 0.f;
    for (int i = idx; i < BN * DD; i += 256 * 256) {
        float d = o[i] - t[i];
        s = fmaf(d, d, s);
    }
    red[tid] = s;
    __syncthreads();
    for (int off = 128; off > 0; off >>= 1) {
        if (tid < off) red[tid] += red[tid + off];
        __syncthreads();
    }
    if (tid == 0) part[blockIdx.x] = red[0];
}

#define DOT16(qa,qb,qc,qd) \
    fmaf(qd.w, pd.w, fmaf(qd.z, pd.z, fmaf(qd.y, pd.y, fmaf(qd.x, pd.x, \
    fmaf(qc.w, pc.w, fmaf(qc.z, pc.z, fmaf(qc.y, pc.y, fmaf(qc.x, pc.x, \
    fmaf(qb.w, pb.w, fmaf(qb.z, pb.z, fmaf(qb.y, pb.y, fmaf(qb.x, pb.x, \
    fmaf(qa.w, pa.w, fmaf(qa.z, pa.z, fmaf(qa.y, pa.y, qa.x * pa.x)))))))))))))))

// ---------------- main: 8 rows per block ----------------
__global__ __launch_bounds__(256, 4) void tsa_kernel(const float* __restrict__ latent,
                                                     const float* __restrict__ raw,
                                                     const float* __restrict__ nrm,
                                                     float* __restrict__ tsa) {
    const int tid  = threadIdx.x;
    const int lane = tid & 63;
    const int w    = tid >> 6;
    const int row0 = blockIdx.x * QB;

    // 36 KB overlay: phase A = minbuf (16 KB), phase B = candidate lists (36 KB),
    // eigen = per-wave scratch (4 x 5 KB). Overlays separated by barriers.
    __shared__ __align__(16) char smem[QB * CAP * 8];
    float (*listV)[CAP] = (float (*)[CAP])smem;
    int   (*listI)[CAP] = (int (*)[CAP])(smem + QB * CAP * 4);
    u64   (*minbuf)[256] = (u64 (*)[256])smem;

    __shared__ int   lcnt[QB];
    __shared__ float Bv[QB];
    __shared__ int   nbr[QB][KNN];

    if (tid < QB) lcnt[tid] = 0;
    __syncthreads();

    const float4* rv4 = (const float4*)raw;

    // ---- queries -> named (block-uniform -> compiler scalarizes) ----
#define LQ(qi) \
    float4 q##qi##a = rv4[(row0 + qi) * 4 + 0]; \
    float4 q##qi##b = rv4[(row0 + qi) * 4 + 1]; \
    float4 q##qi##c = rv4[(row0 + qi) * 4 + 2]; \
    float4 q##qi##d = rv4[(row0 + qi) * 4 + 3]; \
    float qn##qi; { \
        float s = q##qi##a.x * q##qi##a.x; \
        s = fmaf(q##qi##a.y, q##qi##a.y, s); s = fmaf(q##qi##a.z, q##qi##a.z, s); \
        s = fmaf(q##qi##a.w, q##qi##a.w, s); s = fmaf(q##qi##b.x, q##qi##b.x, s); \
        s = fmaf(q##qi##b.y, q##qi##b.y, s); s = fmaf(q##qi##b.z, q##qi##b.z, s); \
        s = fmaf(q##qi##b.w, q##qi##b.w, s); s = fmaf(q##qi##c.x, q##qi##c.x, s); \
        s = fmaf(q##qi##c.y, q##qi##c.y, s); s = fmaf(q##qi##c.z, q##qi##c.z, s); \
        s = fmaf(q##qi##c.w, q##qi##c.w, s); s = fmaf(q##qi##d.x, q##qi##d.x, s); \
        s = fmaf(q##qi##d.y, q##qi##d.y, s); s = fmaf(q##qi##d.z, q##qi##d.z, s); \
        s = fmaf(q##qi##d.w, q##qi##d.w, s); qn##qi = s; }
    LQ(0) LQ(1) LQ(2) LQ(3) LQ(4) LQ(5) LQ(6) LQ(7)

    // ---- phase A: per-thread min over subset [0, MSUB) ----
    u64 km0 = ~0ull, km1 = ~0ull, km2 = ~0ull, km3 = ~0ull;
    u64 km4 = ~0ull, km5 = ~0ull, km6 = ~0ull, km7 = ~0ull;

    for (int j = tid; j < MSUB; j += 256) {
        float4 pa = rv4[j * 4 + 0], pb = rv4[j * 4 + 1];
        float4 pc = rv4[j * 4 + 2], pd = rv4[j * 4 + 3];
        float pn = nrm[j];
#define PHA(qi) { \
        float acc = DOT16(q##qi##a, q##qi##b, q##qi##c, q##qi##d); \
        float d2 = fmaxf(fmaf(-2.f, acc, qn##qi + pn), 0.f); \
        u64 key = (((u64)__float_as_uint(d2)) << 32) | (unsigned)j; \
        if (j != row0 + qi && key < km##qi) km##qi = key; }
        PHA(0) PHA(1) PHA(2) PHA(3) PHA(4) PHA(5) PHA(6) PHA(7)
    }
    minbuf[0][tid] = km0; minbuf[1][tid] = km1; minbuf[2][tid] = km2; minbuf[3][tid] = km3;
    minbuf[4][tid] = km4; minbuf[5][tid] = km5; minbuf[6][tid] = km6; minbuf[7][tid] = km7;
    __syncthreads();

    // ---- bound: 25th smallest of 256 per-thread mins ----
    for (int qq = 0; qq < 2; ++qq) {
        int qi = 2 * w + qq;
        u64 v0 = minbuf[qi][lane];
        u64 v1 = minbuf[qi][lane + 64];
        u64 v2 = minbuf[qi][lane + 128];
        u64 v3 = minbuf[qi][lane + 192];
        u64 bk = ~0ull;
        for (int it = 0; it < KNN; ++it) {
            u64 m = v0 < v1 ? v0 : v1;
            u64 m2 = v2 < v3 ? v2 : v3;
            if (m2 < m) m = m2;
            m = wave_min_u64(m);
            bk = m;
            if (v0 == m) v0 = ~0ull;
            if (v1 == m) v1 = ~0ull;
            if (v2 == m) v2 = ~0ull;
            if (v3 == m) v3 = ~0ull;
        }
        if (lane == 0) Bv[qi] = __uint_as_float((unsigned)(bk >> 32));
    }
    __syncthreads();

    float b0 = Bv[0], b1 = Bv[1], b2 = Bv[2], b3 = Bv[3];
    float b4 = Bv[4], b5 = Bv[5], b6 = Bv[6], b7 = Bv[7];

    // ---- phase B: single full pass, collect d2 <= B ----
    for (int j = tid; j < BN; j += 256) {
        float4 pa = rv4[j * 4 + 0], pb = rv4[j * 4 + 1];
        float4 pc = rv4[j * 4 + 2], pd = rv4[j * 4 + 3];
        float pn = nrm[j];
#define PHB(qi) { \
        float acc = DOT16(q##qi##a, q##qi##b, q##qi##c, q##qi##d); \
        float d2 = fmaxf(fmaf(-2.f, acc, qn##qi + pn), 0.f); \
        if (d2 <= b##qi && j != row0 + qi) { \
            int pos = atomicAdd(&lcnt[qi], 1); \
            if (pos < CAP) { listV[qi][pos] = d2; listI[qi][pos] = j; } } }
        PHB(0) PHB(1) PHB(2) PHB(3) PHB(4) PHB(5) PHB(6) PHB(7)
    }
    __syncthreads();

    // ---- exact top-25 set per query: register-resident extract-min ----
    for (int qq = 0; qq < 2; ++qq) {
        int qi = 2 * w + qq;
        int cnt = lcnt[qi]; if (cnt > CAP) cnt = CAP;
        u64 k0,k1,k2,k3,k4,k5,k6,k7,k8;
#define LK(s) { int e = lane + 64*s; \
        k##s = (e < cnt) ? ((((u64)__float_as_uint(listV[qi][e])) << 32) | (unsigned)listI[qi][e]) : ~0ull; }
        LK(0) LK(1) LK(2) LK(3) LK(4) LK(5) LK(6) LK(7) LK(8)
        for (int it = 0; it < KNN; ++it) {
            u64 best = k0;
            if (k1 < best) best = k1;
            if (k2 < best) best = k2;
            if (k3 < best) best = k3;
            if (k4 < best) best = k4;
            if (k5 < best) best = k5;
            if (k6 < best) best = k6;
            if (k7 < best) best = k7;
            if (k8 < best) best = k8;
            best = wave_min_u64(best);
            if (k0 == best) k0 = ~0ull;
            if (k1 == best) k1 = ~0ull;
            if (k2 == best) k2 = ~0ull;
            if (k3 == best) k3 = ~0ull;
            if (k4 == best) k4 = ~0ull;
            if (k5 == best) k5 = ~0ull;
            if (k6 == best) k6 = ~0ull;
            if (k7 == best) k7 = ~0ull;
            if (k8 == best) k8 = ~0ull;
            if (lane == 0) nbr[qi][it] = (int)(best & 0xffffffffu);
        }
    }
    __syncthreads();   // lists dead; eigen scratch overlays them

    // ---- eigen phase: wave-private scratch, ZERO barriers ----
    // lane (q,j): q = lane>>4, j = lane&15; owns M[4q+r][j], r=0..3
    float* ews  = (float*)smem + w * 1280;
    float* pts  = ews;          // 25 x stride 20  (500)
    float* Arow = ews + 512;    // 16 x stride 20  (320)
    float* Acol = ews + 832;    // 16 x stride 20  (320)
    float* vbuf = ews + 1152;   // 16
    float* ubuf = ews + 1168;   // 2 x 16

    const int q4 = (lane >> 4) << 2;
    const int jc = lane & 15;

    for (int rr = 0; rr < 2; ++rr) {
        int qi = 2 * w + rr;
        for (int m = 0; m < 2; ++m) {
            const float4* src4 = (const float4*)((m == 0) ? latent : raw);
            if (lane < KNN) {
                int nb = nbr[qi][lane];
                float4 r0 = src4[nb * 4 + 0], r1 = src4[nb * 4 + 1];
                float4 r2 = src4[nb * 4 + 2], r3 = src4[nb * 4 + 3];
                float4* dst = (float4*)(pts + lane * 20);
                dst[0] = r0; dst[1] = r1; dst[2] = r2; dst[3] = r3;
            }
            // gram + mean adjustment: C = G - s s^T / 25
            float g0 = 0, g1 = 0, g2 = 0, g3 = 0;
            float s0 = 0, s1 = 0, s2 = 0, s3 = 0, sj = 0;
            for (int k = 0; k < KNN; ++k) {
                float4 qv = *(const float4*)(pts + k * 20 + q4);
                float rj = pts[k * 20 + jc];
                g0 = fmaf(qv.x, rj, g0); g1 = fmaf(qv.y, rj, g1);
                g2 = fmaf(qv.z, rj, g2); g3 = fmaf(qv.w, rj, g3);
                s0 += qv.x; s1 += qv.y; s2 += qv.z; s3 += qv.w; sj += rj;
            }
            const float i25 = 1.0f / 25.0f;
            float sjs = sj * i25;
            float a0 = fmaf(-s0, sjs, g0);
            float a1 = fmaf(-s1, sjs, g1);
            float a2 = fmaf(-s2, sjs, g2);
            float a3 = fmaf(-s3, sjs, g3);

            // 5 trace-normalized squarings (register-blocked, dual LDS layout)
            for (int sq = 0; sq < 5; ++sq) {
                Arow[(q4 + 0) * 20 + jc] = a0;
                Arow[(q4 + 1) * 20 + jc] = a1;
                Arow[(q4 + 2) * 20 + jc] = a2;
                Arow[(q4 + 3) * 20 + jc] = a3;
                *(float4*)(Acol + jc * 20 + q4) = make_float4(a0, a1, a2, a3);
                float t = 0.f;
                if (jc == q4 + 0) t += a0;
                if (jc == q4 + 1) t += a1;
                if (jc == q4 + 2) t += a2;
                if (jc == q4 + 3) t += a3;
#pragma unroll
                for (int off = 32; off >= 1; off >>= 1) t += __shfl_xor(t, off, 64);
                float itr = (t > 0.f) ? (1.0f / t) : 1.0f;
                float b0_ = 0, b1_ = 0, b2_ = 0, b3_ = 0;
#pragma unroll
                for (int k = 0; k < DD; ++k) {
                    float4 ck = *(const float4*)(Acol + k * 20 + q4); // A[4q+r][k]
                    float rk = Arow[k * 20 + jc];                     // A[k][j]
                    b0_ = fmaf(ck.x, rk, b0_);
                    b1_ = fmaf(ck.y, rk, b1_);
                    b2_ = fmaf(ck.z, rk, b2_);
                    b3_ = fmaf(ck.w, rk, b3_);
                }
                float sc = itr * itr;
                a0 = b0_ * sc; a1 = b1_ * sc; a2 = b2_ * sc; a3 = b3_ * sc;
            }

            // column norms + argmax (tie: lower j)
            float cn = a0 * a0;
            cn = fmaf(a1, a1, cn); cn = fmaf(a2, a2, cn); cn = fmaf(a3, a3, cn);
            cn += __shfl_xor(cn, 16, 64);
            cn += __shfl_xor(cn, 32, 64);
            int bj = jc;
#pragma unroll
            for (int off = 32; off >= 1; off >>= 1) {
                float on = __shfl_xor(cn, off, 64);
                int   oj = __shfl_xor(bj, off, 64);
                if (on > cn || (on == cn && oj < bj)) { cn = on; bj = oj; }
            }

            // v0 = column bj of A
            if (jc == bj) {
                vbuf[q4 + 0] = a0; vbuf[q4 + 1] = a1;
                vbuf[q4 + 2] = a2; vbuf[q4 + 3] = a3;
            }
            // matvec 1: w = A v
            float vj = vbuf[jc];
            float w0 = a0 * vj, w1 = a1 * vj, w2 = a2 * vj, w3 = a3 * vj;
#pragma unroll
            for (int off = 1; off < 16; off <<= 1) {
                w0 += __shfl_xor(w0, off, 64);
                w1 += __shfl_xor(w1, off, 64);
                w2 += __shfl_xor(w2, off, 64);
                w3 += __shfl_xor(w3, off, 64);
            }
            if (jc == 0) {
                vbuf[q4 + 0] = w0; vbuf[q4 + 1] = w1;
                vbuf[q4 + 2] = w2; vbuf[q4 + 3] = w3;
            }
            // matvec 2: x = A w
            vj = vbuf[jc];
            float x0 = a0 * vj, x1 = a1 * vj, x2 = a2 * vj, x3 = a3 * vj;
#pragma unroll
            for (int off = 1; off < 16; off <<= 1) {
                x0 += __shfl_xor(x0, off, 64);
                x1 += __shfl_xor(x1, off, 64);
                x2 += __shfl_xor(x2, off, 64);
                x3 += __shfl_xor(x3, off, 64);
            }
            float nv = x0 * x0;
            nv = fmaf(x1, x1, nv); nv = fmaf(x2, x2, nv); nv = fmaf(x3, x3, nv);
            nv += __shfl_xor(nv, 16, 64);
            nv += __shfl_xor(nv, 32, 64);
            float inv = rsqrtf(fmaxf(nv, 1e-30f));
            if (jc == 0) {
                ubuf[m * 16 + q4 + 0] = x0 * inv;
                ubuf[m * 16 + q4 + 1] = x1 * inv;
                ubuf[m * 16 + q4 + 2] = x2 * inv;
                ubuf[m * 16 + q4 + 3] = x3 * inv;
            }
        }
        float du = ubuf[jc] * ubuf[16 + jc];
#pragma unroll
        for (int off = 1; off < 16; off <<= 1) du += __shfl_xor(du, off, 64);
        if (lane == 0) tsa[row0 + qi] = 2.0f - 2.0f * du * du;
    }
}

// ---------------- finalize ----------------
__global__ void finalize_kernel(const float* __restrict__ tsa,
                                const float* __restrict__ part,
                                float* __restrict__ out) {
    __shared__ float red[256];
    int tid = threadIdx.x;
    float s = 0.f;
    for (int i = tid; i < BN; i += 256) s += tsa[i];
    red[tid] = s;
    __syncthreads();
    for (int off = 128; off > 0; off >>= 1) {
        if (tid < off) red[tid] += red[tid + off];
        __syncthreads();
    }
    float tsaSum = red[0];
    __syncthreads();
    red[tid] = part[tid];
    __syncthreads();
    for (int off = 128; off > 0; off >>= 1) {
        if (tid < off) red[tid] += red[tid + off];
        __syncthreads();
    }
    if (tid == 0)
        out[0] = red[0] * (1.0f / (float)(BN * DD)) + 0.1f * (tsaSum * (1.0f / (float)BN));
}

extern "C" void kernel_launch(void* const* d_in, const int* in_sizes, int n_in,
                              void* d_out, int out_size, void* d_ws, size_t ws_size,
                              hipStream_t stream) {
    const float* outputs = (const float*)d_in[0];
    const float* targets = (const float*)d_in[1];
    const float* latent  = (const float*)d_in[2];
    const float* raw     = (const float*)d_in[3];
    float* ws_f = (float*)d_ws;
    float* tsa  = ws_f;            // BN
    float* part = ws_f + BN;       // 256
    float* nrm  = ws_f + BN + 256; // BN

    norms_kernel<<<BN / 256, 256, 0, stream>>>(raw, nrm);
    recon_kernel<<<256, 256, 0, stream>>>(outputs, targets, part);
    tsa_kernel<<<BN / QB, 256, 0, stream>>>(latent, raw, nrm, tsa);
    finalize_kernel<<<1, 256, 0, stream>>>(tsa, part, (float*)d_out);
}